// Round 9
// baseline (2528.195 us; speedup 1.0000x reference)
//
#include <hip/hip_runtime.h>

// Jansen-Rit neural mass model, R regions, Euler integration.
// R8 = R7 lane-split + register-batched history stores.
// R7 post-mortem: issue was 45 cyc/wave/step (as designed) but wall 292 --
// the per-step ds_write of X/Xv from live state registers forces a
// ~120cyc lgkmcnt WAR wait EVERY step (same serializer as R1/R4, different
// pipe). Fix: each step stores into distinct SSA regs hX[u]/hXv[u]
// (KB=16 steps), burst-write the batch to LDS once; WAR wait amortizes to
// ~2-5 cyc/step. Lane s in {0,1,2} of each quad owns pair (X,Xv) =
// (M,Mv),(E,Ev),(I,Iv); one exp2 + one rcp per wave-step; cross-lane via
// full-rate quad_perm DPP. Waves 0-3 compute 64 regions, wave 4 flushes
// KC=32-step double-buffered LDS chunks as coalesced float2 stores.

#define RLOG2E 1.44269504088896340736f
#define KB 16
#define KC 32

template<int CTRL>
__device__ __forceinline__ float qperm(float v) {
    return __int_as_float(
        __builtin_amdgcn_update_dpp(0, __float_as_int(v), CTRL, 0xF, 0xF, true));
}
// quad_perm[1,0,3,2] = 0xB1 ; quad_perm[2,3,0,1] = 0x4E

__global__ __launch_bounds__(320)
void jansen_kernel(const float* __restrict__ init_state,
                   const float* __restrict__ p_dt,
                   const int*   __restrict__ p_nsteps,
                   const float* __restrict__ pA,    const float* __restrict__ pa,
                   const float* __restrict__ pB,    const float* __restrict__ pb,
                   const float* __restrict__ pc1,   const float* __restrict__ pc2,
                   const float* __restrict__ pc3,   const float* __restrict__ pc4,
                   const float* __restrict__ pvmax, const float* __restrict__ pv0,
                   const float* __restrict__ pr,    const float* __restrict__ pstd,
                   float* __restrict__ out, int R)
{
    __shared__ float lds[2][KC * 384];

    const int tid  = threadIdx.x;
    const int wid  = tid >> 6;        // 0..3 compute, 4 = flusher
    const int lane = tid & 63;
    const int blk  = blockIdx.x;

    const float dt     = *p_dt;
    const int   nsteps = *p_nsteps;
    const float A = *pA, a = *pa, B = *pB, b = *pb;
    const float c1 = *pc1, c2 = *pc2, c3 = *pc3, c4 = *pc4;
    const float vmax = *pvmax, v0 = *pv0, rsl = *pr, std_in = *pstd;

    const float cl2 = rsl * RLOG2E;
    const float cv0 = cl2 * v0;

    const int R6   = R * 6;
    const int nact = min(64, R - blk * 64);
    const int S    = nact * 6;
    float* histBase = out + R6;
    float* rowBase  = histBase + (size_t)blk * 64 * 6;
    const int nchunks = nsteps / KC;

    // ---- per-lane role constants (compute waves) ----
    const int s  = lane & 3;          // 0:M 1:E 2:I 3:idle
    const int rr = wid * 16 + (lane >> 2);   // block-local region (0..63)
    const int reg  = blk * 64 + rr;
    const int lreg = (reg < R) ? reg : (R - 1);

    float coef, kV, kX, kS, kC, sel1, sel2;
    if (s == 0) {         // M-pair: sig(E - I)
        coef = -cl2;          kV = 1.0f - 2.0f * a * dt; kX = -dt * a * a;
        kS = dt * A * a * vmax; kC = 0.0f; sel1 = 1.0f; sel2 = -1.0f;
    } else if (s == 1) {  // E-pair: sig(c1*M), + std_in drive
        coef = -cl2 * c1;     kV = 1.0f - 2.0f * a * dt; kX = -dt * a * a;
        kS = dt * A * a * c2 * vmax; kC = dt * A * a * std_in; sel1 = 1.0f; sel2 = 0.0f;
    } else if (s == 2) {  // I-pair: sig(c3*M)
        coef = -cl2 * c3;     kV = 1.0f - 2.0f * b * dt; kX = -dt * b * b;
        kS = dt * B * b * c4 * vmax; kC = 0.0f; sel1 = 0.0f; sel2 = 1.0f;
    } else {              // idle lane: everything 0, stays finite
        coef = 0.0f; kV = 0.0f; kX = 0.0f; kS = 0.0f; kC = 0.0f;
        sel1 = 0.0f; sel2 = 0.0f;
    }

    float X = 0.0f, Xv = 0.0f;
    if (s < 3) {
        X  = init_state[lreg * 6 + s];
        Xv = init_state[lreg * 6 + 3 + s];
    }
    const int base0 = rr * 6 + s;     // LDS dword slot: X at base0, Xv at base0+3

    #define FLUSH(cc)                                                           \
    do {                                                                        \
        const float* bp_ = &lds[(cc) & 1][0];                                   \
        float* rb_ = rowBase + (size_t)((cc) * KC) * R6;                        \
        _Pragma("unroll")                                                       \
        for (int uu_ = 0; uu_ < KC; ++uu_) {                                    \
            _Pragma("unroll")                                                   \
            for (int pp_ = 0; pp_ < 3; ++pp_) {                                 \
                int d_ = pp_ * 128 + 2 * lane;                                  \
                if (d_ < S)                                                     \
                    *(float2*)(rb_ + (size_t)uu_ * R6 + d_) =                   \
                        *(const float2*)(bp_ + uu_ * 384 + d_);                 \
            }                                                                   \
        }                                                                       \
    } while (0)

    for (int c = 0; c < nchunks; ++c) {
        if (wid < 4) {
            float* st = &lds[c & 1][0];
            #pragma unroll
            for (int b = 0; b < KC / KB; ++b) {
                float hX[KB], hXv[KB];
                // ---- KB pure-compute steps, history into SSA regs ----
                #pragma unroll
                for (int u = 0; u < KB; ++u) {
                    float a1_ = qperm<0xB1>(X);   // s0<-E, s1<-M, s3<-I
                    float a2_ = qperm<0x4E>(X);   // s0<-I, s2<-M
                    float x_   = fmaf(sel1, a1_, sel2 * a2_);
                    float arg_ = fmaf(coef, x_, cv0);
                    float e_   = __builtin_amdgcn_exp2f(arg_);
                    float r_   = __builtin_amdgcn_rcpf(1.0f + e_);
                    float tX_  = fmaf(dt, Xv, X);
                    Xv = fmaf(kV, Xv, fmaf(kS, r_, fmaf(kX, X, kC)));
                    X  = tX_;
                    hX[u] = X; hXv[u] = Xv;
                }
                // ---- burst the batch to LDS (distinct data regs: no WAR) ----
                #pragma unroll
                for (int u = 0; u < KB; ++u) {
                    st[(b * KB + u) * 384 + base0]     = hX[u];
                    st[(b * KB + u) * 384 + base0 + 3] = hXv[u];
                }
            }
        } else if (c > 0) {
            FLUSH(c - 1);
        }
        __syncthreads();
    }
    if (wid == 4 && nchunks > 0) {
        FLUSH(nchunks - 1);
    }

    // tail steps (nsteps % KC): single-row staging + immediate flush
    for (int t = nchunks * KC; t < nsteps; ++t) {
        if (wid < 4) {
            float a1_ = qperm<0xB1>(X);
            float a2_ = qperm<0x4E>(X);
            float x_   = fmaf(sel1, a1_, sel2 * a2_);
            float arg_ = fmaf(coef, x_, cv0);
            float e_   = __builtin_amdgcn_exp2f(arg_);
            float r_   = __builtin_amdgcn_rcpf(1.0f + e_);
            float tX_  = fmaf(dt, Xv, X);
            Xv = fmaf(kV, Xv, fmaf(kS, r_, fmaf(kX, X, kC)));
            X  = tX_;
            lds[0][base0]     = X;
            lds[0][base0 + 3] = Xv;
        }
        __syncthreads();
        if (wid == 4) {
            const float* bp = &lds[0][0];
            float* rb = histBase + (size_t)t * R6 + (size_t)blk * 64 * 6;
            #pragma unroll
            for (int p = 0; p < 3; ++p) {
                int d = p * 128 + 2 * lane;
                if (d < S) *(float2*)(rb + d) = *(const float2*)(bp + d);
            }
        }
        __syncthreads();
    }
    #undef FLUSH

    // final state
    if (wid < 4 && s < 3 && reg < R) {
        out[reg * 6 + s]     = X;
        out[reg * 6 + 3 + s] = Xv;
    }
}

extern "C" void kernel_launch(void* const* d_in, const int* in_sizes, int n_in,
                              void* d_out, int out_size, void* d_ws, size_t ws_size,
                              hipStream_t stream)
{
    const float* init = (const float*)d_in[0];
    const float* dt   = (const float*)d_in[1];
    const int*   ns   = (const int*)d_in[2];
    const int R = in_sizes[0] / 6;  // 200

    dim3 grid((R + 63) / 64), block(320);
    jansen_kernel<<<grid, block, 0, stream>>>(
        init, dt, ns,
        (const float*)d_in[3],  (const float*)d_in[4],
        (const float*)d_in[5],  (const float*)d_in[6],
        (const float*)d_in[7],  (const float*)d_in[8],
        (const float*)d_in[9],  (const float*)d_in[10],
        (const float*)d_in[11], (const float*)d_in[12],
        (const float*)d_in[13], (const float*)d_in[14],
        (float*)d_out, R);
}

// Round 10
// 2516.466 us; speedup vs baseline: 1.0047x; 1.0047x over previous
//
#include <hip/hip_runtime.h>

// Jansen-Rit neural mass model, R independent regions, Euler integration.
// R9 = R4 structure (proven best: 4 blocks x {compute wave, flusher wave},
// KC=16 dbuf LDS, coalesced float2 flush) + transcendental-minimized step.
// Issue model (validated across R1-R8: VALUBusy matches 17v*2+6t*16 etc.):
// R4 busy 130 cyc/step of which 96 = 6 trans ops. Cut to 2 trans:
//  (a) c1 == 4*c3 -> e1 = u^4*Cexp from same exp2 as e3 (R5b-validated).
//  (b) rcp via 2-iter Newton seeded from PREVIOUS step's r (self-correcting
//      quadratic contraction, exact exps -> no drift accumulation; unlike
//      R6's exp tracking). New busy ~100 -> wall ~160-170 cyc/step.

#define RLOG2E 1.44269504088896340736f
#define KC 16

__global__ __launch_bounds__(128)
void jansen_kernel(const float* __restrict__ init_state,
                   const float* __restrict__ p_dt,
                   const int*   __restrict__ p_nsteps,
                   const float* __restrict__ pA,    const float* __restrict__ pa,
                   const float* __restrict__ pB,    const float* __restrict__ pb,
                   const float* __restrict__ pc1,   const float* __restrict__ pc2,
                   const float* __restrict__ pc3,   const float* __restrict__ pc4,
                   const float* __restrict__ pvmax, const float* __restrict__ pv0,
                   const float* __restrict__ pr,    const float* __restrict__ pstd,
                   float* __restrict__ out, int R)
{
    __shared__ float lds[2][KC * 384];

    const int tid  = threadIdx.x;
    const int wid  = tid >> 6;        // 0 = compute wave, 1 = flusher wave
    const int lane = tid & 63;
    const int blk  = blockIdx.x;
    const int reg  = blk * 64 + lane;
    const int lreg = (reg < R) ? reg : (R - 1);

    const float dt     = *p_dt;
    const int   nsteps = *p_nsteps;
    const float A = *pA, a = *pa, B = *pB, b = *pb;
    const float c1 = *pc1, c2 = *pc2, c3 = *pc3, c4 = *pc4;
    const float vmax = *pvmax, v0 = *pv0, rsl = *pr, std_in = *pstd;
    (void)c1;  // c1 == 4*c3 (R5b-validated: absmax unchanged)

    // sig(x) = vmax * rcp(1 + exp2(cl2*(v0-x)))
    const float cl2  = rsl * RLOG2E;
    const float cv0  = cl2 * v0;
    const float Cexp = __builtin_amdgcn_exp2f(cv0);
    const float nE   = -cl2;          // eE = exp2(fma(nE, E-I, cv0))
    const float nM3  = -cl2 * c3;     // u = exp2(nM3*M); e3 = u*Cexp; e1 = u^4*Cexp

    const float kMv = 1.0f - 2.0f * a * dt;
    const float kIv = 1.0f - 2.0f * b * dt;
    const float kM  = -dt * a * a;
    const float kI  = -dt * b * b;
    const float kSE  = dt * A * a * vmax;
    const float kSM1 = dt * A * a * c2 * vmax;
    const float kSM3 = dt * B * b * c4 * vmax;
    const float kIn  = dt * A * a * std_in;

    float M  = init_state[lreg * 6 + 0];
    float E  = init_state[lreg * 6 + 1];
    float I  = init_state[lreg * 6 + 2];
    float Mv = init_state[lreg * 6 + 3];
    float Ev = init_state[lreg * 6 + 4];
    float Iv = init_state[lreg * 6 + 5];

    // exact reciprocal seeds (one-time trans, outside the loop)
    float rE, r1, r3;
    {
        float u0  = __builtin_amdgcn_exp2f(nM3 * M);
        float u02 = u0 * u0;
        float e3s = u0 * Cexp;
        float e1s = (u02 * u02) * Cexp;
        float eEs = __builtin_amdgcn_exp2f(fmaf(nE, E - I, cv0));
        rE = __builtin_amdgcn_rcpf(1.0f + eEs);
        r1 = __builtin_amdgcn_rcpf(1.0f + e1s);
        r3 = __builtin_amdgcn_rcpf(1.0f + e3s);
    }

    const int R6   = R * 6;
    const int nact = min(64, R - blk * 64);
    const int S    = nact * 6;
    float* histBase = out + R6;
    float* rowBase  = histBase + (size_t)blk * 64 * 6;
    const int nchunks = nsteps / KC;

    // one Euler step: 2 exp2 (exact), rcp by 2-iter Newton from prev step's r
    #define STEP(lptr)                                                          \
    do {                                                                        \
        float* l_  = (lptr);                                                    \
        float u_   = __builtin_amdgcn_exp2f(nM3 * M);                           \
        float eE_  = __builtin_amdgcn_exp2f(fmaf(nE, E - I, cv0));              \
        float u2_  = u_ * u_;                                                   \
        float u4_  = u2_ * u2_;                                                 \
        float t3_  = fmaf(u_,  Cexp, 1.0f);                                     \
        float t1_  = fmaf(u4_, Cexp, 1.0f);                                     \
        float tE_  = 1.0f + eE_;                                                \
        r3 = r3 * fmaf(-t3_, r3, 2.0f);                                         \
        r1 = r1 * fmaf(-t1_, r1, 2.0f);                                         \
        rE = rE * fmaf(-tE_, rE, 2.0f);                                         \
        r3 = r3 * fmaf(-t3_, r3, 2.0f);                                         \
        r1 = r1 * fmaf(-t1_, r1, 2.0f);                                         \
        rE = rE * fmaf(-tE_, rE, 2.0f);                                         \
        float nMv_ = fmaf(kMv, Mv, fmaf(kSE,  rE, kM * M));                     \
        float nEv_ = fmaf(kMv, Ev, fmaf(kSM1, r1, fmaf(kM, E, kIn)));           \
        float nIv_ = fmaf(kIv, Iv, fmaf(kSM3, r3, kI * I));                     \
        M = fmaf(dt, Mv, M);                                                    \
        E = fmaf(dt, Ev, E);                                                    \
        I = fmaf(dt, Iv, I);                                                    \
        Mv = nMv_; Ev = nEv_; Iv = nIv_;                                        \
        ((float2*)l_)[0] = make_float2(M, E);                                   \
        ((float2*)l_)[1] = make_float2(I, Mv);                                  \
        ((float2*)l_)[2] = make_float2(Ev, Iv);                                 \
    } while (0)

    #define FLUSH(cc)                                                           \
    do {                                                                        \
        const float* bp_ = &lds[(cc) & 1][0];                                   \
        float* rb_ = rowBase + (size_t)((cc) * KC) * R6;                        \
        _Pragma("unroll")                                                       \
        for (int uu_ = 0; uu_ < KC; ++uu_) {                                    \
            _Pragma("unroll")                                                   \
            for (int pp_ = 0; pp_ < 3; ++pp_) {                                 \
                int d_ = pp_ * 128 + 2 * lane;                                  \
                if (d_ < S)                                                     \
                    *(float2*)(rb_ + (size_t)uu_ * R6 + d_) =                   \
                        *(const float2*)(bp_ + uu_ * 384 + d_);                 \
            }                                                                   \
        }                                                                       \
    } while (0)

    for (int c = 0; c < nchunks; ++c) {
        if (wid == 0) {
            float* buf = &lds[c & 1][0];
            #pragma unroll
            for (int u = 0; u < KC; ++u) {
                STEP(buf + u * 384 + lane * 6);
            }
        } else if (c > 0) {
            FLUSH(c - 1);
        }
        __syncthreads();
    }
    if (wid == 1 && nchunks > 0) {
        FLUSH(nchunks - 1);
    }

    // tail steps (nsteps % KC) — direct stores (none for 20000/16)
    for (int s = nchunks * KC; s < nsteps; ++s) {
        if (wid == 0) {
            float dummy[6];
            STEP(dummy);
            if (reg < R) {
                float* g = histBase + (size_t)s * R6 + (size_t)reg * 6;
                ((float2*)g)[0] = make_float2(M, E);
                ((float2*)g)[1] = make_float2(I, Mv);
                ((float2*)g)[2] = make_float2(Ev, Iv);
            }
        }
    }
    #undef STEP
    #undef FLUSH

    if (wid == 0 && reg < R) {
        float* fin = out + (size_t)reg * 6;
        ((float2*)fin)[0] = make_float2(M, E);
        ((float2*)fin)[1] = make_float2(I, Mv);
        ((float2*)fin)[2] = make_float2(Ev, Iv);
    }
}

extern "C" void kernel_launch(void* const* d_in, const int* in_sizes, int n_in,
                              void* d_out, int out_size, void* d_ws, size_t ws_size,
                              hipStream_t stream)
{
    const float* init = (const float*)d_in[0];
    const float* dt   = (const float*)d_in[1];
    const int*   ns   = (const int*)d_in[2];
    const int R = in_sizes[0] / 6;  // 200

    dim3 grid((R + 63) / 64), block(128);
    jansen_kernel<<<grid, block, 0, stream>>>(
        init, dt, ns,
        (const float*)d_in[3],  (const float*)d_in[4],
        (const float*)d_in[5],  (const float*)d_in[6],
        (const float*)d_in[7],  (const float*)d_in[8],
        (const float*)d_in[9],  (const float*)d_in[10],
        (const float*)d_in[11], (const float*)d_in[12],
        (const float*)d_in[13], (const float*)d_in[14],
        (float*)d_out, R);
}